// Round 12
// baseline (387.179 us; speedup 1.0000x reference)
//
#include <hip/hip_runtime.h>
#include <math.h>

#define NB 64        // batch
#define IFD 1024     // in features
#define PP 128       // P (num keys)
#define PSD 2048     // PS0/PS1
#define PK 64        // PKEY
#define NFD 64       // NF
#define DELTAF 1e-6f

typedef __bf16 bf16x8 __attribute__((ext_vector_type(8)));
typedef float f32x4 __attribute__((ext_vector_type(4)));
typedef unsigned short ushort;

static __device__ __forceinline__ ushort f2bf(float f) {
    unsigned int u = __float_as_uint(f);
    u = (u + 0x7FFF + ((u >> 16) & 1)) >> 16;   // RTNE
    return (ushort)u;
}
static __device__ __forceinline__ unsigned int pack2bf(float a, float b) {
    return (unsigned int)f2bf(a) | ((unsigned int)f2bf(b) << 16);
}
static __device__ __forceinline__ bf16x8 ld8cvt(const float* p) {
    float a[8];
    __builtin_memcpy(a, p, 32);
    bf16x8 r;
    #pragma unroll
    for (int i = 0; i < 8; ++i) r[i] = (__bf16)a[i];
    return r;
}

// ---------------------------------------------------------------------------
// Kernel 1 (FUSED): k_proj + k_mpt in one launch.  (R10/R11 config, unchanged.)
// ---------------------------------------------------------------------------
__global__ __launch_bounds__(256) void k_prep(
    const float* __restrict__ x,
    const float* __restrict__ Wu, const float* __restrict__ bu,
    const float* __restrict__ Wv, const float* __restrict__ bv,
    const float* __restrict__ Ws, const float* __restrict__ bs,
    const float* __restrict__ PMU, const float* __restrict__ PMV,
    float* __restrict__ ko, ushort* __restrict__ MPt)
{
    const int id = blockIdx.x;
    const int t = threadIdx.x;

    __shared__ ushort Tl[64][40];

    if (id < 192) {
        const int comp = id / 64;
        const int xb = id % 64;
        const float* W    = comp == 0 ? Wu : (comp == 1 ? Wv : Ws);
        const float* bias = comp == 0 ? bu : (comp == 1 ? bv : bs);
        float* out = ko + (size_t)comp * NB * 4096;

        const int w = t >> 6, l = t & 63;
        const int n0 = xb * 64 + w * 16;
        const int lr = l & 15, lk8 = (l >> 4) * 8;

        f32x4 acc[4] = {};
        #pragma unroll 4
        for (int kk = 0; kk < IFD; kk += 32) {
            bf16x8 bw = ld8cvt(&W[(size_t)(n0 + lr) * IFD + kk + lk8]);
            #pragma unroll
            for (int fi = 0; fi < 4; ++fi) {
                bf16x8 af = ld8cvt(&x[(size_t)(fi * 16 + lr) * IFD + kk + lk8]);
                acc[fi] = __builtin_amdgcn_mfma_f32_16x16x32_bf16(af, bw, acc[fi], 0, 0, 0);
            }
        }
        const int rb = (l >> 4) * 4, cl = l & 15;
        const int n = n0 + cl;
        const float bv_ = bias[n];
        #pragma unroll
        for (int fi = 0; fi < 4; ++fi)
            #pragma unroll
            for (int r = 0; r < 4; ++r)
                out[(size_t)(fi * 16 + rb + r) * 4096 + n] = acc[fi][r] + bv_;
    } else {
        const int mid = id - 192;
        const int comp = mid >> 7;
        const int rem = mid & 127;
        const float* PM = comp == 0 ? PMU : PMV;
        ushort* dst = MPt + (size_t)comp * PSD * PP;
        const int n0 = (rem & 31) * 64;
        const int p0 = (rem >> 5) * 32;
        const int nl = t & 63, pq = t >> 6;
        #pragma unroll
        for (int it = 0; it < 8; ++it) {
            const int pp = pq * 8 + it;
            Tl[nl][pp] = f2bf(PM[(size_t)(p0 + pp) * (PK + PSD) + PK + n0 + nl]);
        }
        __syncthreads();
        const int r = t >> 2, c = (t & 3) * 8;
        *(f32x4*)&dst[(size_t)(n0 + r) * PP + p0 + c] = *(const f32x4*)&Tl[r][c];
    }
}

// ---------------------------------------------------------------------------
// Kernel 2 (MFMA, FUSED): theta + softmax + (d @ MP^T); comp-0 blocks also
// recompute s inline.  (R10/R11 config, unchanged.)
// ---------------------------------------------------------------------------
__global__ __launch_bounds__(256) void k_theta_mp(
    const float* __restrict__ ko,
    const float* __restrict__ PMU, const float* __restrict__ PMV,
    const float* __restrict__ PMS,
    const ushort* __restrict__ MPt,
    ushort* __restrict__ UsT, ushort* __restrict__ VsT)
{
    const int g = blockIdx.x;
    const int q = blockIdx.y;
    const int comp = blockIdx.z;
    const float* PM = comp == 0 ? PMU : PMV;
    const int stride = PK + PSD;
    const ushort* B = MPt + (size_t)comp * PSD * PP;
    ushort* C = (comp == 0 ? UsT : VsT) + (size_t)g * PSD * NFD;
    const float* kg = ko + ((size_t)comp * NB + g) * 4096;

    __shared__ float an_s[128], bn_s[64];
    __shared__ ushort d_lds[64][136];
    __shared__ float mpS[128], vrow[64], s_sh[64];
    const int t = threadIdx.x;
    if (t < 128) {
        const float* row = PM + (size_t)t * stride;
        float ss = 0.f;
        #pragma unroll
        for (int k = 0; k < PK; ++k) { float v = row[k]; ss += v * v; }
        an_s[t] = sqrtf(ss) + DELTAF;
    }
    if (t < 64) {
        float ss = 0.f;
        #pragma unroll
        for (int k = 0; k < PK; ++k) { float v = kg[t * PK + k]; ss += v * v; }
        bn_s[t] = sqrtf(ss) + DELTAF;
    }
    __syncthreads();

    const int w = t >> 6, l = t & 63;
    const int lr = l & 15, lk8 = (l >> 4) * 8;
    const int rb = (l >> 4) * 4, cl = l & 15;

    {
        f32x4 acc0[8] = {};
        #pragma unroll
        for (int kk = 0; kk < 2; ++kk) {
            bf16x8 af = ld8cvt(&kg[(size_t)(w * 16 + lr) * PK + kk * 32 + lk8]);
            #pragma unroll
            for (int fj = 0; fj < 8; ++fj) {
                bf16x8 bw = ld8cvt(&PM[(size_t)(fj * 16 + lr) * stride + kk * 32 + lk8]);
                acc0[fj] = __builtin_amdgcn_mfma_f32_16x16x32_bf16(af, bw, acc0[fj], 0, 0, 0);
            }
        }
        float dv[8][4];
        #pragma unroll
        for (int fj = 0; fj < 8; ++fj) {
            const float an_v = an_s[fj * 16 + cl];
            #pragma unroll
            for (int r = 0; r < 4; ++r)
                dv[fj][r] = acc0[fj][r] / (64.f * bn_s[w * 16 + rb + r] * an_v + DELTAF);
        }
        #pragma unroll
        for (int r = 0; r < 4; ++r) {
            float m = dv[0][r];
            #pragma unroll
            for (int fj = 1; fj < 8; ++fj) m = fmaxf(m, dv[fj][r]);
            #pragma unroll
            for (int msk = 1; msk < 16; msk <<= 1) m = fmaxf(m, __shfl_xor(m, msk, 64));
            float s = 0.f;
            #pragma unroll
            for (int fj = 0; fj < 8; ++fj) { dv[fj][r] = expf(dv[fj][r] - m); s += dv[fj][r]; }
            #pragma unroll
            for (int msk = 1; msk < 16; msk <<= 1) s += __shfl_xor(s, msk, 64);
            const float inv = 1.f / s;
            #pragma unroll
            for (int fj = 0; fj < 8; ++fj) dv[fj][r] *= inv;
        }
        #pragma unroll
        for (int fj = 0; fj < 8; ++fj)
            #pragma unroll
            for (int r = 0; r < 4; ++r)
                d_lds[w * 16 + rb + r][fj * 16 + cl] = f2bf(dv[fj][r]);
    }

    if (comp == 0) {
        __syncthreads();
        const float* kg2 = ko + ((size_t)2 * NB + g) * 4096;
        const int strideS = PK + 1;
        if (t < 128) {
            const float* row = PMS + (size_t)t * strideS;
            float ss = 0.f;
            #pragma unroll
            for (int k = 0; k < PK; ++k) { float v = row[k]; ss += v * v; }
            an_s[t] = sqrtf(ss) + DELTAF;
        }
        if (t < 64) {
            float ss = 0.f;
            #pragma unroll
            for (int k = 0; k < PK; ++k) { float v = kg2[t * PK + k]; ss += v * v; }
            bn_s[t] = sqrtf(ss) + DELTAF;
        }
        if (t >= 128) mpS[t - 128] = PMS[(size_t)(t - 128) * strideS + PK];
        __syncthreads();

        f32x4 accS[8] = {};
        #pragma unroll
        for (int kk = 0; kk < 2; ++kk) {
            bf16x8 af = ld8cvt(&kg2[(size_t)(w * 16 + lr) * PK + kk * 32 + lk8]);
            #pragma unroll
            for (int fj = 0; fj < 8; ++fj) {
                bf16x8 bw = ld8cvt(&PMS[(size_t)(fj * 16 + lr) * strideS + kk * 32 + lk8]);
                accS[fj] = __builtin_amdgcn_mfma_f32_16x16x32_bf16(af, bw, accS[fj], 0, 0, 0);
            }
        }
        float dvS[8][4];
        #pragma unroll
        for (int fj = 0; fj < 8; ++fj) {
            const float an_v = an_s[fj * 16 + cl];
            #pragma unroll
            for (int r = 0; r < 4; ++r)
                dvS[fj][r] = accS[fj][r] / (64.f * bn_s[w * 16 + rb + r] * an_v + DELTAF);
        }
        #pragma unroll
        for (int r = 0; r < 4; ++r) {
            float m = dvS[0][r];
            #pragma unroll
            for (int fj = 1; fj < 8; ++fj) m = fmaxf(m, dvS[fj][r]);
            #pragma unroll
            for (int msk = 1; msk < 16; msk <<= 1) m = fmaxf(m, __shfl_xor(m, msk, 64));
            float s = 0.f;
            #pragma unroll
            for (int fj = 0; fj < 8; ++fj) { dvS[fj][r] = expf(dvS[fj][r] - m); s += dvS[fj][r]; }
            #pragma unroll
            for (int msk = 1; msk < 16; msk <<= 1) s += __shfl_xor(s, msk, 64);
            const float inv = 1.f / s;
            #pragma unroll
            for (int fj = 0; fj < 8; ++fj) dvS[fj][r] *= inv;
        }
        #pragma unroll
        for (int r = 0; r < 4; ++r) {
            float v = 0.f;
            #pragma unroll
            for (int fj = 0; fj < 8; ++fj) v += dvS[fj][r] * mpS[fj * 16 + cl];
            #pragma unroll
            for (int msk = 1; msk < 16; msk <<= 1) v += __shfl_xor(v, msk, 64);
            if ((l & 15) == 0) vrow[w * 16 + rb + r] = v;
        }
        __syncthreads();
        if (t < 64) {
            float v = vrow[t];
            float sp = (v > 20.f) ? v : log1pf(expf(v));
            #pragma unroll
            for (int o = 1; o < 64; o <<= 1) {
                float u = __shfl_up(sp, o, 64);
                if (t >= o) sp += u;
            }
            s_sh[t] = sp;
        }
    }
    __syncthreads();

    bf16x8 af[4][4];
    #pragma unroll
    for (int fg = 0; fg < 4; ++fg)
        #pragma unroll
        for (int kk = 0; kk < 4; ++kk)
            af[fg][kk] = *(const bf16x8*)&d_lds[fg * 16 + lr][kk * 32 + lk8];

    const int nwb = q * 512 + w * 128;
    #pragma unroll
    for (int ch = 0; ch < 8; ++ch) {
        f32x4 acc[4] = {};
        #pragma unroll
        for (int kk = 0; kk < 4; ++kk) {
            bf16x8 bw = *(const bf16x8*)&B[(size_t)(nwb + ch * 16 + lr) * PP + kk * 32 + lk8];
            #pragma unroll
            for (int fg = 0; fg < 4; ++fg)
                acc[fg] = __builtin_amdgcn_mfma_f32_16x16x32_bf16(af[fg][kk], bw, acc[fg], 0, 0, 0);
        }
        const int n = nwb + ch * 16 + cl;
        #pragma unroll
        for (int fg = 0; fg < 4; ++fg) {
            const int f0 = fg * 16 + rb;
            f32x4 sc;
            if (comp == 0) sc = *(const f32x4*)&s_sh[f0];
            else           sc = (f32x4){1.f, 1.f, 1.f, 1.f};
            uint2 pk;
            pk.x = pack2bf(acc[fg][0] * sc[0], acc[fg][1] * sc[1]);
            pk.y = pack2bf(acc[fg][2] * sc[2], acc[fg][3] * sc[3]);
            *(uint2*)&C[(size_t)n * NFD + f0] = pk;
        }
    }
}

// ---------------------------------------------------------------------------
// Kernel 3 (MFMA): Wrec[b] = Us[b]^T @ Vs[b].
// Retile 32x1024 -> 64x512 (same grid 8192, 512 thr): per-block B-slab read
// halves again (128 KB -> 64 KB) => total B traffic 1 GB -> 0.5 GB, further
// relieving the read/write fabric contention R11 proved was the limiter.
// Wave w: rows [i0+(w&3)*16, +16), cols [jbase+(w>>2)*256, +256) -> 16 frags.
// LDS bounce 32 KB/pass, 4 passes; NT dwordx4 stores, 2 KB contiguous/row.
// Per-output kk-ascending accumulation unchanged -> bit-identical.
// ---------------------------------------------------------------------------
__global__ __launch_bounds__(512) void k_wrec(
    const ushort* __restrict__ UsT, const ushort* __restrict__ VsT,
    float* __restrict__ out)
{
    const int lin = blockIdx.x;
    const int nl2 = (lin & 7) * 1024 + (lin >> 3);   // bijective (8192 % 8 == 0)
    const int b = nl2 >> 7;                          // 128 tiles per batch
    const int rem = nl2 & 127;                       // 32 row-tiles x 4 col-tiles
    const int i0 = (rem >> 2) * 64;
    const int jbase = (rem & 3) * 512;

    const int w = threadIdx.x >> 6, l = threadIdx.x & 63;
    const int wrow = (w & 3) * 16;      // row-frag within tile
    const int wcol = (w >> 2) * 256;    // col-half within tile
    const int lr = l & 15, lk8 = (l >> 4) * 8;
    const ushort* A  = UsT + (size_t)b * PSD * NFD;
    const ushort* Bp = VsT + (size_t)b * PSD * NFD;

    // Transposed mfma(bw, af): lane (l&15) = output row, (l>>4)*4+reg = cols.
    f32x4 acc[16] = {};
    #pragma unroll
    for (int kk = 0; kk < 2; ++kk) {
        bf16x8 af = *(const bf16x8*)&A[(size_t)(i0 + wrow + lr) * NFD + kk * 32 + lk8];
        #pragma unroll
        for (int fj = 0; fj < 16; ++fj) {
            bf16x8 bw = *(const bf16x8*)&Bp[(size_t)(jbase + wcol + fj * 16 + lr) * NFD + kk * 32 + lk8];
            acc[fj] = __builtin_amdgcn_mfma_f32_16x16x32_bf16(bw, af, acc[fj], 0, 0, 0);
        }
    }

    __shared__ float lds[16 * 512];     // 32 KB: one 16-row pass
    const int cl = l & 15, rbq = l >> 4;
    float* ob = out + (size_t)b * (size_t)PSD * PSD;

    #pragma unroll
    for (int p = 0; p < 4; ++p) {
        if ((w & 3) == p) {             // the 2 waves owning rows p*16.. write
            #pragma unroll
            for (int fj = 0; fj < 16; ++fj) {
                const int colbase = wcol + fj * 16 + rbq * 4;
                *(f32x4*)&lds[cl * 512 + (colbase ^ ((cl & 7) << 2))] = acc[fj];
            }
        }
        __syncthreads();
        const int r = 2 * w + (l >> 5);           // wave w -> rows 2w, 2w+1
        const int swz = (r & 7) << 2;
        #pragma unroll
        for (int inst = 0; inst < 4; ++inst) {
            const int c = (l & 31) * 4 + inst * 128;
            f32x4 v = *(const f32x4*)&lds[r * 512 + (c ^ swz)];
            __builtin_nontemporal_store(v,
                (f32x4*)&ob[(size_t)(i0 + p * 16 + r) * PSD + jbase + c]);
        }
        __syncthreads();
    }
}

// ---------------------------------------------------------------------------
extern "C" void kernel_launch(void* const* d_in, const int* in_sizes, int n_in,
                              void* d_out, int out_size, void* d_ws, size_t ws_size,
                              hipStream_t stream)
{
    const float* x   = (const float*)d_in[0];
    const float* PMU = (const float*)d_in[1];
    const float* PMV = (const float*)d_in[2];
    const float* PMS = (const float*)d_in[3];
    const float* Wku = (const float*)d_in[4];
    const float* bku = (const float*)d_in[5];
    const float* Wkv = (const float*)d_in[6];
    const float* bkv = (const float*)d_in[7];
    const float* Wks = (const float*)d_in[8];
    const float* bks = (const float*)d_in[9];
    float* out = (float*)d_out;

    char* ws = (char*)d_ws;
    float*  ko   = (float*)(ws);                                 // 3 MiB
    ushort* MPt  = (ushort*)(ws + (size_t)5 * 1024 * 1024);      // 1 MiB
    ushort* UsT  = (ushort*)(ws + (size_t)8 * 1024 * 1024);      // 16 MiB
    ushort* VsT  = (ushort*)(ws + (size_t)24 * 1024 * 1024);     // 16 MiB

    k_prep    <<<448,            256, 0, stream>>>(x, Wku, bku, Wkv, bkv, Wks, bks,
                                                   PMU, PMV, ko, MPt);
    k_theta_mp<<<dim3(64, 4, 2), 256, 0, stream>>>(ko, PMU, PMV, PMS, MPt, UsT, VsT);
    k_wrec    <<<8192,           512, 0, stream>>>(UsT, VsT, out);
}

// Round 13
// 302.230 us; speedup vs baseline: 1.2811x; 1.2811x over previous
//
#include <hip/hip_runtime.h>
#include <math.h>

#define NB 64        // batch
#define IFD 1024     // in features
#define PP 128       // P (num keys)
#define PSD 2048     // PS0/PS1
#define PK 64        // PKEY
#define NFD 64       // NF
#define DELTAF 1e-6f

typedef __bf16 bf16x8 __attribute__((ext_vector_type(8)));
typedef float f32x4 __attribute__((ext_vector_type(4)));
typedef unsigned short ushort;

static __device__ __forceinline__ ushort f2bf(float f) {
    unsigned int u = __float_as_uint(f);
    u = (u + 0x7FFF + ((u >> 16) & 1)) >> 16;   // RTNE
    return (ushort)u;
}
static __device__ __forceinline__ unsigned int pack2bf(float a, float b) {
    return (unsigned int)f2bf(a) | ((unsigned int)f2bf(b) << 16);
}
static __device__ __forceinline__ bf16x8 ld8cvt(const float* p) {
    float a[8];
    __builtin_memcpy(a, p, 32);
    bf16x8 r;
    #pragma unroll
    for (int i = 0; i < 8; ++i) r[i] = (__bf16)a[i];
    return r;
}

// ---------------------------------------------------------------------------
// Kernel 1 (FUSED): k_proj + k_mpt in one launch.  (R11 config, unchanged.)
// ---------------------------------------------------------------------------
__global__ __launch_bounds__(256) void k_prep(
    const float* __restrict__ x,
    const float* __restrict__ Wu, const float* __restrict__ bu,
    const float* __restrict__ Wv, const float* __restrict__ bv,
    const float* __restrict__ Ws, const float* __restrict__ bs,
    const float* __restrict__ PMU, const float* __restrict__ PMV,
    float* __restrict__ ko, ushort* __restrict__ MPt)
{
    const int id = blockIdx.x;
    const int t = threadIdx.x;

    __shared__ ushort Tl[64][40];

    if (id < 192) {
        const int comp = id / 64;
        const int xb = id % 64;
        const float* W    = comp == 0 ? Wu : (comp == 1 ? Wv : Ws);
        const float* bias = comp == 0 ? bu : (comp == 1 ? bv : bs);
        float* out = ko + (size_t)comp * NB * 4096;

        const int w = t >> 6, l = t & 63;
        const int n0 = xb * 64 + w * 16;
        const int lr = l & 15, lk8 = (l >> 4) * 8;

        f32x4 acc[4] = {};
        #pragma unroll 4
        for (int kk = 0; kk < IFD; kk += 32) {
            bf16x8 bw = ld8cvt(&W[(size_t)(n0 + lr) * IFD + kk + lk8]);
            #pragma unroll
            for (int fi = 0; fi < 4; ++fi) {
                bf16x8 af = ld8cvt(&x[(size_t)(fi * 16 + lr) * IFD + kk + lk8]);
                acc[fi] = __builtin_amdgcn_mfma_f32_16x16x32_bf16(af, bw, acc[fi], 0, 0, 0);
            }
        }
        const int rb = (l >> 4) * 4, cl = l & 15;
        const int n = n0 + cl;
        const float bv_ = bias[n];
        #pragma unroll
        for (int fi = 0; fi < 4; ++fi)
            #pragma unroll
            for (int r = 0; r < 4; ++r)
                out[(size_t)(fi * 16 + rb + r) * 4096 + n] = acc[fi][r] + bv_;
    } else {
        const int mid = id - 192;
        const int comp = mid >> 7;
        const int rem = mid & 127;
        const float* PM = comp == 0 ? PMU : PMV;
        ushort* dst = MPt + (size_t)comp * PSD * PP;
        const int n0 = (rem & 31) * 64;
        const int p0 = (rem >> 5) * 32;
        const int nl = t & 63, pq = t >> 6;
        #pragma unroll
        for (int it = 0; it < 8; ++it) {
            const int pp = pq * 8 + it;
            Tl[nl][pp] = f2bf(PM[(size_t)(p0 + pp) * (PK + PSD) + PK + n0 + nl]);
        }
        __syncthreads();
        const int r = t >> 2, c = (t & 3) * 8;
        *(f32x4*)&dst[(size_t)(n0 + r) * PP + p0 + c] = *(const f32x4*)&Tl[r][c];
    }
}

// ---------------------------------------------------------------------------
// Kernel 2 (MFMA, FUSED): theta + softmax + (d @ MP^T); comp-0 blocks also
// recompute s inline.  (R11 config, unchanged.)
// ---------------------------------------------------------------------------
__global__ __launch_bounds__(256) void k_theta_mp(
    const float* __restrict__ ko,
    const float* __restrict__ PMU, const float* __restrict__ PMV,
    const float* __restrict__ PMS,
    const ushort* __restrict__ MPt,
    ushort* __restrict__ UsT, ushort* __restrict__ VsT)
{
    const int g = blockIdx.x;
    const int q = blockIdx.y;
    const int comp = blockIdx.z;
    const float* PM = comp == 0 ? PMU : PMV;
    const int stride = PK + PSD;
    const ushort* B = MPt + (size_t)comp * PSD * PP;
    ushort* C = (comp == 0 ? UsT : VsT) + (size_t)g * PSD * NFD;
    const float* kg = ko + ((size_t)comp * NB + g) * 4096;

    __shared__ float an_s[128], bn_s[64];
    __shared__ ushort d_lds[64][136];
    __shared__ float mpS[128], vrow[64], s_sh[64];
    const int t = threadIdx.x;
    if (t < 128) {
        const float* row = PM + (size_t)t * stride;
        float ss = 0.f;
        #pragma unroll
        for (int k = 0; k < PK; ++k) { float v = row[k]; ss += v * v; }
        an_s[t] = sqrtf(ss) + DELTAF;
    }
    if (t < 64) {
        float ss = 0.f;
        #pragma unroll
        for (int k = 0; k < PK; ++k) { float v = kg[t * PK + k]; ss += v * v; }
        bn_s[t] = sqrtf(ss) + DELTAF;
    }
    __syncthreads();

    const int w = t >> 6, l = t & 63;
    const int lr = l & 15, lk8 = (l >> 4) * 8;
    const int rb = (l >> 4) * 4, cl = l & 15;

    {
        f32x4 acc0[8] = {};
        #pragma unroll
        for (int kk = 0; kk < 2; ++kk) {
            bf16x8 af = ld8cvt(&kg[(size_t)(w * 16 + lr) * PK + kk * 32 + lk8]);
            #pragma unroll
            for (int fj = 0; fj < 8; ++fj) {
                bf16x8 bw = ld8cvt(&PM[(size_t)(fj * 16 + lr) * stride + kk * 32 + lk8]);
                acc0[fj] = __builtin_amdgcn_mfma_f32_16x16x32_bf16(af, bw, acc0[fj], 0, 0, 0);
            }
        }
        float dv[8][4];
        #pragma unroll
        for (int fj = 0; fj < 8; ++fj) {
            const float an_v = an_s[fj * 16 + cl];
            #pragma unroll
            for (int r = 0; r < 4; ++r)
                dv[fj][r] = acc0[fj][r] / (64.f * bn_s[w * 16 + rb + r] * an_v + DELTAF);
        }
        #pragma unroll
        for (int r = 0; r < 4; ++r) {
            float m = dv[0][r];
            #pragma unroll
            for (int fj = 1; fj < 8; ++fj) m = fmaxf(m, dv[fj][r]);
            #pragma unroll
            for (int msk = 1; msk < 16; msk <<= 1) m = fmaxf(m, __shfl_xor(m, msk, 64));
            float s = 0.f;
            #pragma unroll
            for (int fj = 0; fj < 8; ++fj) { dv[fj][r] = expf(dv[fj][r] - m); s += dv[fj][r]; }
            #pragma unroll
            for (int msk = 1; msk < 16; msk <<= 1) s += __shfl_xor(s, msk, 64);
            const float inv = 1.f / s;
            #pragma unroll
            for (int fj = 0; fj < 8; ++fj) dv[fj][r] *= inv;
        }
        #pragma unroll
        for (int fj = 0; fj < 8; ++fj)
            #pragma unroll
            for (int r = 0; r < 4; ++r)
                d_lds[w * 16 + rb + r][fj * 16 + cl] = f2bf(dv[fj][r]);
    }

    if (comp == 0) {
        __syncthreads();
        const float* kg2 = ko + ((size_t)2 * NB + g) * 4096;
        const int strideS = PK + 1;
        if (t < 128) {
            const float* row = PMS + (size_t)t * strideS;
            float ss = 0.f;
            #pragma unroll
            for (int k = 0; k < PK; ++k) { float v = row[k]; ss += v * v; }
            an_s[t] = sqrtf(ss) + DELTAF;
        }
        if (t < 64) {
            float ss = 0.f;
            #pragma unroll
            for (int k = 0; k < PK; ++k) { float v = kg2[t * PK + k]; ss += v * v; }
            bn_s[t] = sqrtf(ss) + DELTAF;
        }
        if (t >= 128) mpS[t - 128] = PMS[(size_t)(t - 128) * strideS + PK];
        __syncthreads();

        f32x4 accS[8] = {};
        #pragma unroll
        for (int kk = 0; kk < 2; ++kk) {
            bf16x8 af = ld8cvt(&kg2[(size_t)(w * 16 + lr) * PK + kk * 32 + lk8]);
            #pragma unroll
            for (int fj = 0; fj < 8; ++fj) {
                bf16x8 bw = ld8cvt(&PMS[(size_t)(fj * 16 + lr) * strideS + kk * 32 + lk8]);
                accS[fj] = __builtin_amdgcn_mfma_f32_16x16x32_bf16(af, bw, accS[fj], 0, 0, 0);
            }
        }
        float dvS[8][4];
        #pragma unroll
        for (int fj = 0; fj < 8; ++fj) {
            const float an_v = an_s[fj * 16 + cl];
            #pragma unroll
            for (int r = 0; r < 4; ++r)
                dvS[fj][r] = accS[fj][r] / (64.f * bn_s[w * 16 + rb + r] * an_v + DELTAF);
        }
        #pragma unroll
        for (int r = 0; r < 4; ++r) {
            float m = dvS[0][r];
            #pragma unroll
            for (int fj = 1; fj < 8; ++fj) m = fmaxf(m, dvS[fj][r]);
            #pragma unroll
            for (int msk = 1; msk < 16; msk <<= 1) m = fmaxf(m, __shfl_xor(m, msk, 64));
            float s = 0.f;
            #pragma unroll
            for (int fj = 0; fj < 8; ++fj) { dvS[fj][r] = expf(dvS[fj][r] - m); s += dvS[fj][r]; }
            #pragma unroll
            for (int msk = 1; msk < 16; msk <<= 1) s += __shfl_xor(s, msk, 64);
            const float inv = 1.f / s;
            #pragma unroll
            for (int fj = 0; fj < 8; ++fj) dvS[fj][r] *= inv;
        }
        #pragma unroll
        for (int r = 0; r < 4; ++r) {
            float v = 0.f;
            #pragma unroll
            for (int fj = 0; fj < 8; ++fj) v += dvS[fj][r] * mpS[fj * 16 + cl];
            #pragma unroll
            for (int msk = 1; msk < 16; msk <<= 1) v += __shfl_xor(v, msk, 64);
            if ((l & 15) == 0) vrow[w * 16 + rb + r] = v;
        }
        __syncthreads();
        if (t < 64) {
            float v = vrow[t];
            float sp = (v > 20.f) ? v : log1pf(expf(v));
            #pragma unroll
            for (int o = 1; o < 64; o <<= 1) {
                float u = __shfl_up(sp, o, 64);
                if (t >= o) sp += u;
            }
            s_sh[t] = sp;
        }
    }
    __syncthreads();

    bf16x8 af[4][4];
    #pragma unroll
    for (int fg = 0; fg < 4; ++fg)
        #pragma unroll
        for (int kk = 0; kk < 4; ++kk)
            af[fg][kk] = *(const bf16x8*)&d_lds[fg * 16 + lr][kk * 32 + lk8];

    const int nwb = q * 512 + w * 128;
    #pragma unroll
    for (int ch = 0; ch < 8; ++ch) {
        f32x4 acc[4] = {};
        #pragma unroll
        for (int kk = 0; kk < 4; ++kk) {
            bf16x8 bw = *(const bf16x8*)&B[(size_t)(nwb + ch * 16 + lr) * PP + kk * 32 + lk8];
            #pragma unroll
            for (int fg = 0; fg < 4; ++fg)
                acc[fg] = __builtin_amdgcn_mfma_f32_16x16x32_bf16(af[fg][kk], bw, acc[fg], 0, 0, 0);
        }
        const int n = nwb + ch * 16 + cl;
        #pragma unroll
        for (int fg = 0; fg < 4; ++fg) {
            const int f0 = fg * 16 + rb;
            f32x4 sc;
            if (comp == 0) sc = *(const f32x4*)&s_sh[f0];
            else           sc = (f32x4){1.f, 1.f, 1.f, 1.f};
            uint2 pk;
            pk.x = pack2bf(acc[fg][0] * sc[0], acc[fg][1] * sc[1]);
            pk.y = pack2bf(acc[fg][2] * sc[2], acc[fg][3] * sc[3]);
            *(uint2*)&C[(size_t)n * NFD + f0] = pk;
        }
    }
}

// ---------------------------------------------------------------------------
// Kernel 3 (MFMA): Wrec[b] = Us[b]^T @ Vs[b].
// 64x1024 tile, 1024 threads = 16 waves.  Halves B-read traffic vs R11
// (each B fragment register-reused across 4 row-fragments) while KEEPING
// R11's proven write structure: 4 KB chunks, every wave writes LDS every
// pass.  Wave w: rows [i0, i0+64) (4 frags), cols [jbase + w*64, +64).
// A-slab (8 KB) is read identically by all 16 waves -> L1 broadcast.
// Per-output kk-ascending accumulation unchanged -> bit-identical.
// grid 4096 (64 tiles/batch), XCD batch-chunk swizzle (4096 % 8 == 0).
// ---------------------------------------------------------------------------
__global__ __launch_bounds__(1024) void k_wrec(
    const ushort* __restrict__ UsT, const ushort* __restrict__ VsT,
    float* __restrict__ out)
{
    const int lin = blockIdx.x;
    const int nl2 = (lin & 7) * 512 + (lin >> 3);    // bijective
    const int b = nl2 >> 6;                          // 64 tiles per batch
    const int rem = nl2 & 63;                        // 32 row-tiles x 2 col-tiles
    const int i0 = (rem >> 1) * 64;
    const int jbase = (rem & 1) * 1024;

    const int w = threadIdx.x >> 6, l = threadIdx.x & 63;
    const int j0 = jbase + w * 64;
    const int lr = l & 15, lk8 = (l >> 4) * 8;
    const ushort* A  = UsT + (size_t)b * PSD * NFD;
    const ushort* Bp = VsT + (size_t)b * PSD * NFD;

    // Transposed mfma(bw, af): lane (l&15) = output row, (l>>4)*4+reg = cols.
    f32x4 acc[4][4] = {};
    #pragma unroll
    for (int kk = 0; kk < 2; ++kk) {
        bf16x8 af[4];
        #pragma unroll
        for (int fi = 0; fi < 4; ++fi)
            af[fi] = *(const bf16x8*)&A[(size_t)(i0 + fi * 16 + lr) * NFD + kk * 32 + lk8];
        #pragma unroll
        for (int fj = 0; fj < 4; ++fj) {
            bf16x8 bw = *(const bf16x8*)&Bp[(size_t)(j0 + fj * 16 + lr) * NFD + kk * 32 + lk8];
            #pragma unroll
            for (int fi = 0; fi < 4; ++fi)
                acc[fi][fj] = __builtin_amdgcn_mfma_f32_16x16x32_bf16(bw, af[fi], acc[fi][fj], 0, 0, 0);
        }
    }

    __shared__ float lds[16 * 1024];    // 64 KB: one 16-row pass
    const int cl = l & 15, rbq = l >> 4;
    float* ob = out + (size_t)b * (size_t)PSD * PSD;

    #pragma unroll
    for (int p = 0; p < 4; ++p) {
        // ALL 16 waves write their fi=p fragments (64-col slice each)
        #pragma unroll
        for (int fj = 0; fj < 4; ++fj) {
            const int colbase = w * 64 + fj * 16 + rbq * 4;
            *(f32x4*)&lds[cl * 1024 + (colbase ^ ((cl & 7) << 2))] = acc[p][fj];
        }
        __syncthreads();
        // wave w reads back row w (4 KB contiguous) and NT-stores it
        const int swz = (w & 7) << 2;
        #pragma unroll
        for (int inst = 0; inst < 4; ++inst) {
            const int c = l * 4 + inst * 256;
            f32x4 v = *(const f32x4*)&lds[w * 1024 + (c ^ swz)];
            __builtin_nontemporal_store(v,
                (f32x4*)&ob[(size_t)(i0 + p * 16 + w) * PSD + jbase + c]);
        }
        __syncthreads();
    }
}

// ---------------------------------------------------------------------------
extern "C" void kernel_launch(void* const* d_in, const int* in_sizes, int n_in,
                              void* d_out, int out_size, void* d_ws, size_t ws_size,
                              hipStream_t stream)
{
    const float* x   = (const float*)d_in[0];
    const float* PMU = (const float*)d_in[1];
    const float* PMV = (const float*)d_in[2];
    const float* PMS = (const float*)d_in[3];
    const float* Wku = (const float*)d_in[4];
    const float* bku = (const float*)d_in[5];
    const float* Wkv = (const float*)d_in[6];
    const float* bkv = (const float*)d_in[7];
    const float* Wks = (const float*)d_in[8];
    const float* bks = (const float*)d_in[9];
    float* out = (float*)d_out;

    char* ws = (char*)d_ws;
    float*  ko   = (float*)(ws);                                 // 3 MiB
    ushort* MPt  = (ushort*)(ws + (size_t)5 * 1024 * 1024);      // 1 MiB
    ushort* UsT  = (ushort*)(ws + (size_t)8 * 1024 * 1024);      // 16 MiB
    ushort* VsT  = (ushort*)(ws + (size_t)24 * 1024 * 1024);     // 16 MiB

    k_prep    <<<448,            256, 0, stream>>>(x, Wku, bku, Wkv, bkv, Wks, bks,
                                                   PMU, PMV, ko, MPt);
    k_theta_mp<<<dim3(64, 4, 2), 256, 0, stream>>>(ko, PMU, PMV, PMS, MPt, UsT, VsT);
    k_wrec    <<<4096,          1024, 0, stream>>>(UsT, VsT, out);
}

// Round 14
// 283.833 us; speedup vs baseline: 1.3641x; 1.0648x over previous
//
#include <hip/hip_runtime.h>
#include <math.h>

#define NB 64        // batch
#define IFD 1024     // in features
#define PP 128       // P (num keys)
#define PSD 2048     // PS0/PS1
#define PK 64        // PKEY
#define NFD 64       // NF
#define DELTAF 1e-6f

typedef __bf16 bf16x8 __attribute__((ext_vector_type(8)));
typedef float f32x4 __attribute__((ext_vector_type(4)));
typedef unsigned short ushort;

static __device__ __forceinline__ ushort f2bf(float f) {
    unsigned int u = __float_as_uint(f);
    u = (u + 0x7FFF + ((u >> 16) & 1)) >> 16;   // RTNE
    return (ushort)u;
}
static __device__ __forceinline__ unsigned int pack2bf(float a, float b) {
    return (unsigned int)f2bf(a) | ((unsigned int)f2bf(b) << 16);
}
static __device__ __forceinline__ bf16x8 ld8cvt(const float* p) {
    float a[8];
    __builtin_memcpy(a, p, 32);
    bf16x8 r;
    #pragma unroll
    for (int i = 0; i < 8; ++i) r[i] = (__bf16)a[i];
    return r;
}

// ---------------------------------------------------------------------------
// Kernel 1 (FUSED): k_proj + k_mpt in one launch.  (R11 config, unchanged.)
// ---------------------------------------------------------------------------
__global__ __launch_bounds__(256) void k_prep(
    const float* __restrict__ x,
    const float* __restrict__ Wu, const float* __restrict__ bu,
    const float* __restrict__ Wv, const float* __restrict__ bv,
    const float* __restrict__ Ws, const float* __restrict__ bs,
    const float* __restrict__ PMU, const float* __restrict__ PMV,
    float* __restrict__ ko, ushort* __restrict__ MPt)
{
    const int id = blockIdx.x;
    const int t = threadIdx.x;

    __shared__ ushort Tl[64][40];

    if (id < 192) {
        const int comp = id / 64;
        const int xb = id % 64;
        const float* W    = comp == 0 ? Wu : (comp == 1 ? Wv : Ws);
        const float* bias = comp == 0 ? bu : (comp == 1 ? bv : bs);
        float* out = ko + (size_t)comp * NB * 4096;

        const int w = t >> 6, l = t & 63;
        const int n0 = xb * 64 + w * 16;
        const int lr = l & 15, lk8 = (l >> 4) * 8;

        f32x4 acc[4] = {};
        #pragma unroll 4
        for (int kk = 0; kk < IFD; kk += 32) {
            bf16x8 bw = ld8cvt(&W[(size_t)(n0 + lr) * IFD + kk + lk8]);
            #pragma unroll
            for (int fi = 0; fi < 4; ++fi) {
                bf16x8 af = ld8cvt(&x[(size_t)(fi * 16 + lr) * IFD + kk + lk8]);
                acc[fi] = __builtin_amdgcn_mfma_f32_16x16x32_bf16(af, bw, acc[fi], 0, 0, 0);
            }
        }
        const int rb = (l >> 4) * 4, cl = l & 15;
        const int n = n0 + cl;
        const float bv_ = bias[n];
        #pragma unroll
        for (int fi = 0; fi < 4; ++fi)
            #pragma unroll
            for (int r = 0; r < 4; ++r)
                out[(size_t)(fi * 16 + rb + r) * 4096 + n] = acc[fi][r] + bv_;
    } else {
        const int mid = id - 192;
        const int comp = mid >> 7;
        const int rem = mid & 127;
        const float* PM = comp == 0 ? PMU : PMV;
        ushort* dst = MPt + (size_t)comp * PSD * PP;
        const int n0 = (rem & 31) * 64;
        const int p0 = (rem >> 5) * 32;
        const int nl = t & 63, pq = t >> 6;
        #pragma unroll
        for (int it = 0; it < 8; ++it) {
            const int pp = pq * 8 + it;
            Tl[nl][pp] = f2bf(PM[(size_t)(p0 + pp) * (PK + PSD) + PK + n0 + nl]);
        }
        __syncthreads();
        const int r = t >> 2, c = (t & 3) * 8;
        *(f32x4*)&dst[(size_t)(n0 + r) * PP + p0 + c] = *(const f32x4*)&Tl[r][c];
    }
}

// ---------------------------------------------------------------------------
// Kernel 2 (MFMA, FUSED): theta + softmax + (d @ MP^T); comp-0 blocks also
// recompute s inline.  (R11 config, unchanged.)
// ---------------------------------------------------------------------------
__global__ __launch_bounds__(256) void k_theta_mp(
    const float* __restrict__ ko,
    const float* __restrict__ PMU, const float* __restrict__ PMV,
    const float* __restrict__ PMS,
    const ushort* __restrict__ MPt,
    ushort* __restrict__ UsT, ushort* __restrict__ VsT)
{
    const int g = blockIdx.x;
    const int q = blockIdx.y;
    const int comp = blockIdx.z;
    const float* PM = comp == 0 ? PMU : PMV;
    const int stride = PK + PSD;
    const ushort* B = MPt + (size_t)comp * PSD * PP;
    ushort* C = (comp == 0 ? UsT : VsT) + (size_t)g * PSD * NFD;
    const float* kg = ko + ((size_t)comp * NB + g) * 4096;

    __shared__ float an_s[128], bn_s[64];
    __shared__ ushort d_lds[64][136];
    __shared__ float mpS[128], vrow[64], s_sh[64];
    const int t = threadIdx.x;
    if (t < 128) {
        const float* row = PM + (size_t)t * stride;
        float ss = 0.f;
        #pragma unroll
        for (int k = 0; k < PK; ++k) { float v = row[k]; ss += v * v; }
        an_s[t] = sqrtf(ss) + DELTAF;
    }
    if (t < 64) {
        float ss = 0.f;
        #pragma unroll
        for (int k = 0; k < PK; ++k) { float v = kg[t * PK + k]; ss += v * v; }
        bn_s[t] = sqrtf(ss) + DELTAF;
    }
    __syncthreads();

    const int w = t >> 6, l = t & 63;
    const int lr = l & 15, lk8 = (l >> 4) * 8;
    const int rb = (l >> 4) * 4, cl = l & 15;

    {
        f32x4 acc0[8] = {};
        #pragma unroll
        for (int kk = 0; kk < 2; ++kk) {
            bf16x8 af = ld8cvt(&kg[(size_t)(w * 16 + lr) * PK + kk * 32 + lk8]);
            #pragma unroll
            for (int fj = 0; fj < 8; ++fj) {
                bf16x8 bw = ld8cvt(&PM[(size_t)(fj * 16 + lr) * stride + kk * 32 + lk8]);
                acc0[fj] = __builtin_amdgcn_mfma_f32_16x16x32_bf16(af, bw, acc0[fj], 0, 0, 0);
            }
        }
        float dv[8][4];
        #pragma unroll
        for (int fj = 0; fj < 8; ++fj) {
            const float an_v = an_s[fj * 16 + cl];
            #pragma unroll
            for (int r = 0; r < 4; ++r)
                dv[fj][r] = acc0[fj][r] / (64.f * bn_s[w * 16 + rb + r] * an_v + DELTAF);
        }
        #pragma unroll
        for (int r = 0; r < 4; ++r) {
            float m = dv[0][r];
            #pragma unroll
            for (int fj = 1; fj < 8; ++fj) m = fmaxf(m, dv[fj][r]);
            #pragma unroll
            for (int msk = 1; msk < 16; msk <<= 1) m = fmaxf(m, __shfl_xor(m, msk, 64));
            float s = 0.f;
            #pragma unroll
            for (int fj = 0; fj < 8; ++fj) { dv[fj][r] = expf(dv[fj][r] - m); s += dv[fj][r]; }
            #pragma unroll
            for (int msk = 1; msk < 16; msk <<= 1) s += __shfl_xor(s, msk, 64);
            const float inv = 1.f / s;
            #pragma unroll
            for (int fj = 0; fj < 8; ++fj) dv[fj][r] *= inv;
        }
        #pragma unroll
        for (int fj = 0; fj < 8; ++fj)
            #pragma unroll
            for (int r = 0; r < 4; ++r)
                d_lds[w * 16 + rb + r][fj * 16 + cl] = f2bf(dv[fj][r]);
    }

    if (comp == 0) {
        __syncthreads();
        const float* kg2 = ko + ((size_t)2 * NB + g) * 4096;
        const int strideS = PK + 1;
        if (t < 128) {
            const float* row = PMS + (size_t)t * strideS;
            float ss = 0.f;
            #pragma unroll
            for (int k = 0; k < PK; ++k) { float v = row[k]; ss += v * v; }
            an_s[t] = sqrtf(ss) + DELTAF;
        }
        if (t < 64) {
            float ss = 0.f;
            #pragma unroll
            for (int k = 0; k < PK; ++k) { float v = kg2[t * PK + k]; ss += v * v; }
            bn_s[t] = sqrtf(ss) + DELTAF;
        }
        if (t >= 128) mpS[t - 128] = PMS[(size_t)(t - 128) * strideS + PK];
        __syncthreads();

        f32x4 accS[8] = {};
        #pragma unroll
        for (int kk = 0; kk < 2; ++kk) {
            bf16x8 af = ld8cvt(&kg2[(size_t)(w * 16 + lr) * PK + kk * 32 + lk8]);
            #pragma unroll
            for (int fj = 0; fj < 8; ++fj) {
                bf16x8 bw = ld8cvt(&PMS[(size_t)(fj * 16 + lr) * strideS + kk * 32 + lk8]);
                accS[fj] = __builtin_amdgcn_mfma_f32_16x16x32_bf16(af, bw, accS[fj], 0, 0, 0);
            }
        }
        float dvS[8][4];
        #pragma unroll
        for (int fj = 0; fj < 8; ++fj) {
            const float an_v = an_s[fj * 16 + cl];
            #pragma unroll
            for (int r = 0; r < 4; ++r)
                dvS[fj][r] = accS[fj][r] / (64.f * bn_s[w * 16 + rb + r] * an_v + DELTAF);
        }
        #pragma unroll
        for (int r = 0; r < 4; ++r) {
            float m = dvS[0][r];
            #pragma unroll
            for (int fj = 1; fj < 8; ++fj) m = fmaxf(m, dvS[fj][r]);
            #pragma unroll
            for (int msk = 1; msk < 16; msk <<= 1) m = fmaxf(m, __shfl_xor(m, msk, 64));
            float s = 0.f;
            #pragma unroll
            for (int fj = 0; fj < 8; ++fj) { dvS[fj][r] = expf(dvS[fj][r] - m); s += dvS[fj][r]; }
            #pragma unroll
            for (int msk = 1; msk < 16; msk <<= 1) s += __shfl_xor(s, msk, 64);
            const float inv = 1.f / s;
            #pragma unroll
            for (int fj = 0; fj < 8; ++fj) dvS[fj][r] *= inv;
        }
        #pragma unroll
        for (int r = 0; r < 4; ++r) {
            float v = 0.f;
            #pragma unroll
            for (int fj = 0; fj < 8; ++fj) v += dvS[fj][r] * mpS[fj * 16 + cl];
            #pragma unroll
            for (int msk = 1; msk < 16; msk <<= 1) v += __shfl_xor(v, msk, 64);
            if ((l & 15) == 0) vrow[w * 16 + rb + r] = v;
        }
        __syncthreads();
        if (t < 64) {
            float v = vrow[t];
            float sp = (v > 20.f) ? v : log1pf(expf(v));
            #pragma unroll
            for (int o = 1; o < 64; o <<= 1) {
                float u = __shfl_up(sp, o, 64);
                if (t >= o) sp += u;
            }
            s_sh[t] = sp;
        }
    }
    __syncthreads();

    bf16x8 af[4][4];
    #pragma unroll
    for (int fg = 0; fg < 4; ++fg)
        #pragma unroll
        for (int kk = 0; kk < 4; ++kk)
            af[fg][kk] = *(const bf16x8*)&d_lds[fg * 16 + lr][kk * 32 + lk8];

    const int nwb = q * 512 + w * 128;
    #pragma unroll
    for (int ch = 0; ch < 8; ++ch) {
        f32x4 acc[4] = {};
        #pragma unroll
        for (int kk = 0; kk < 4; ++kk) {
            bf16x8 bw = *(const bf16x8*)&B[(size_t)(nwb + ch * 16 + lr) * PP + kk * 32 + lk8];
            #pragma unroll
            for (int fg = 0; fg < 4; ++fg)
                acc[fg] = __builtin_amdgcn_mfma_f32_16x16x32_bf16(af[fg][kk], bw, acc[fg], 0, 0, 0);
        }
        const int n = nwb + ch * 16 + cl;
        #pragma unroll
        for (int fg = 0; fg < 4; ++fg) {
            const int f0 = fg * 16 + rb;
            f32x4 sc;
            if (comp == 0) sc = *(const f32x4*)&s_sh[f0];
            else           sc = (f32x4){1.f, 1.f, 1.f, 1.f};
            uint2 pk;
            pk.x = pack2bf(acc[fg][0] * sc[0], acc[fg][1] * sc[1]);
            pk.y = pack2bf(acc[fg][2] * sc[2], acc[fg][3] * sc[3]);
            *(uint2*)&C[(size_t)n * NFD + f0] = pk;
        }
    }
}

// ---------------------------------------------------------------------------
// Kernel 3 (MFMA): Wrec[b] = Us[b]^T @ Vs[b].  EXACT R11 config (measured
// best, 284 us total): 32x1024 tile, grid 8192, 512 thr = 8 waves.
// Wave w: rows [i0, i0+32) as 2 row-frags, cols [jbase + w*128, +128).
// 2-pass LDS bounce (64 KB), 4 KB contiguous NT dwordx4 chunks per row,
// XCD batch-chunk swizzle.  R12 (64x512) and R13 (64x1024 @1024thr) both
// regressed — B-read-halving does not pay beyond this block shape.
// ---------------------------------------------------------------------------
__global__ __launch_bounds__(512) void k_wrec(
    const ushort* __restrict__ UsT, const ushort* __restrict__ VsT,
    float* __restrict__ out)
{
    const int lin = blockIdx.x;
    const int nl2 = (lin & 7) * 1024 + (lin >> 3);   // bijective (8192 % 8 == 0)
    const int b = nl2 >> 7;                          // 128 tiles per batch
    const int rem = nl2 & 127;
    const int i0 = (rem >> 1) * 32;
    const int jbase = (rem & 1) * 1024;

    const int w = threadIdx.x >> 6, l = threadIdx.x & 63;
    const int j0 = jbase + w * 128;
    const int lr = l & 15, lk8 = (l >> 4) * 8;
    const ushort* A  = UsT + (size_t)b * PSD * NFD;
    const ushort* Bp = VsT + (size_t)b * PSD * NFD;

    // Transposed mfma(bw, af): lane (l&15) = output row (af's row),
    // (l>>4)*4+reg = output col within the bw fragment.
    f32x4 acc[2][8] = {};
    #pragma unroll
    for (int kk = 0; kk < 2; ++kk) {
        bf16x8 af0 = *(const bf16x8*)&A[(size_t)(i0 + lr) * NFD + kk * 32 + lk8];
        bf16x8 af1 = *(const bf16x8*)&A[(size_t)(i0 + 16 + lr) * NFD + kk * 32 + lk8];
        #pragma unroll
        for (int fj = 0; fj < 8; ++fj) {
            bf16x8 bw = *(const bf16x8*)&Bp[(size_t)(j0 + fj * 16 + lr) * NFD + kk * 32 + lk8];
            acc[0][fj] = __builtin_amdgcn_mfma_f32_16x16x32_bf16(bw, af0, acc[0][fj], 0, 0, 0);
            acc[1][fj] = __builtin_amdgcn_mfma_f32_16x16x32_bf16(bw, af1, acc[1][fj], 0, 0, 0);
        }
    }

    __shared__ float lds[16 * 1024];    // 64 KB: one 16-row half
    const int cl = l & 15, rbq = l >> 4;
    float* ob = out + (size_t)b * (size_t)PSD * PSD;

    #pragma unroll
    for (int h = 0; h < 2; ++h) {
        // all 8 waves write their fi=h fragments: 16 rows x 1024 cols
        #pragma unroll
        for (int fj = 0; fj < 8; ++fj) {
            const int colbase = w * 128 + fj * 16 + rbq * 4;
            *(f32x4*)&lds[cl * 1024 + (colbase ^ ((cl & 7) << 2))] = acc[h][fj];
        }
        __syncthreads();
        const int r = 2 * w + (l >> 5);           // wave w -> rows 2w, 2w+1
        const int swz = (r & 7) << 2;
        #pragma unroll
        for (int inst = 0; inst < 8; ++inst) {
            const int c = (l & 31) * 4 + inst * 128;
            f32x4 v = *(const f32x4*)&lds[r * 1024 + (c ^ swz)];
            __builtin_nontemporal_store(v,
                (f32x4*)&ob[(size_t)(i0 + h * 16 + r) * PSD + jbase + c]);
        }
        __syncthreads();
    }
}

// ---------------------------------------------------------------------------
extern "C" void kernel_launch(void* const* d_in, const int* in_sizes, int n_in,
                              void* d_out, int out_size, void* d_ws, size_t ws_size,
                              hipStream_t stream)
{
    const float* x   = (const float*)d_in[0];
    const float* PMU = (const float*)d_in[1];
    const float* PMV = (const float*)d_in[2];
    const float* PMS = (const float*)d_in[3];
    const float* Wku = (const float*)d_in[4];
    const float* bku = (const float*)d_in[5];
    const float* Wkv = (const float*)d_in[6];
    const float* bkv = (const float*)d_in[7];
    const float* Wks = (const float*)d_in[8];
    const float* bks = (const float*)d_in[9];
    float* out = (float*)d_out;

    char* ws = (char*)d_ws;
    float*  ko   = (float*)(ws);                                 // 3 MiB
    ushort* MPt  = (ushort*)(ws + (size_t)5 * 1024 * 1024);      // 1 MiB
    ushort* UsT  = (ushort*)(ws + (size_t)8 * 1024 * 1024);      // 16 MiB
    ushort* VsT  = (ushort*)(ws + (size_t)24 * 1024 * 1024);     // 16 MiB

    k_prep    <<<448,            256, 0, stream>>>(x, Wku, bku, Wkv, bkv, Wks, bks,
                                                   PMU, PMV, ko, MPt);
    k_theta_mp<<<dim3(64, 4, 2), 256, 0, stream>>>(ko, PMU, PMV, PMS, MPt, UsT, VsT);
    k_wrec    <<<8192,           512, 0, stream>>>(UsT, VsT, out);
}